// Round 4
// baseline (655.279 us; speedup 1.0000x reference)
//
#include <hip/hip_runtime.h>
#include <stdint.h>

typedef __attribute__((ext_vector_type(8))) short bf16x8;
typedef __attribute__((ext_vector_type(4))) float f32x4;

__device__ __forceinline__ float bf2f(unsigned short u) {
  union { unsigned int i; float f; } x; x.i = ((unsigned int)u) << 16; return x.f;
}
__device__ __forceinline__ unsigned short f2bf(float f) {
  union { float f; unsigned int i; } x; x.f = f;
  unsigned int i = x.i;
  return (unsigned short)((i + 0x7FFFu + ((i >> 16) & 1u)) >> 16);  // RNE
}

// ---------------- CSR build ----------------

__global__ void count_kernel(const int* __restrict__ ei, int E, int* __restrict__ counts) {
  int e = blockIdx.x * blockDim.x + threadIdx.x;
  if (e < E) atomicAdd(&counts[ei[E + e]], 1);
}

__global__ void scan1_kernel(const int* __restrict__ counts, int n, int* __restrict__ bsum) {
  int i = blockIdx.x * 256 + threadIdx.x;
  int v = (i < n) ? counts[i] : 0;
  int lane = threadIdx.x & 63, w = threadIdx.x >> 6;
  for (int d = 32; d > 0; d >>= 1) v += __shfl_down(v, d, 64);
  __shared__ int ws[4];
  if (lane == 0) ws[w] = v;
  __syncthreads();
  if (threadIdx.x == 0) bsum[blockIdx.x] = ws[0] + ws[1] + ws[2] + ws[3];
}

__global__ void scan2_kernel(int* __restrict__ bsum, int G) {
  int t = threadIdx.x;
  int c = (G + 511) >> 9;
  int lo = min(t * c, G), hi = min(lo + c, G);
  int s = 0;
  for (int i = lo; i < hi; ++i) s += bsum[i];
  int lane = t & 63, w = t >> 6;
  int incl = s;
  for (int d = 1; d < 64; d <<= 1) { int u = __shfl_up(incl, d, 64); if (lane >= d) incl += u; }
  __shared__ int wsum[8];
  if (lane == 63) wsum[w] = incl;
  __syncthreads();
  int wpre = 0;
  for (int i = 0; i < w; ++i) wpre += wsum[i];
  int excl = wpre + incl - s;
  for (int i = lo; i < hi; ++i) { int v = bsum[i]; bsum[i] = excl; excl += v; }
}

__global__ void scan3_kernel(const int* __restrict__ counts, int n, const int* __restrict__ bsum,
                             int* __restrict__ offsets, int* __restrict__ cursor, int total) {
  int i = blockIdx.x * 256 + threadIdx.x;
  int v = (i < n) ? counts[i] : 0;
  int lane = threadIdx.x & 63, w = threadIdx.x >> 6;
  int incl = v;
  for (int d = 1; d < 64; d <<= 1) { int u = __shfl_up(incl, d, 64); if (lane >= d) incl += u; }
  __shared__ int wsum[4];
  if (lane == 63) wsum[w] = incl;
  __syncthreads();
  int pre = bsum[blockIdx.x];
  for (int j = 0; j < w; ++j) pre += wsum[j];
  if (i < n) {
    int excl = pre + incl - v;
    offsets[i] = excl;
    cursor[i] = excl;
  }
  if (i == 0) offsets[n] = total;
}

__global__ void fill_kernel(const int* __restrict__ ei, const float* __restrict__ pseudo,
                            int E, int* __restrict__ cursor, int* __restrict__ src_s,
                            float2* __restrict__ ps_s) {
  int e = blockIdx.x * blockDim.x + threadIdx.x;
  if (e >= E) return;
  int d = ei[E + e];
  int s = ei[e];
  int p = atomicAdd(&cursor[d], 1);
  src_s[p] = s;
  ps_s[p] = ((const float2*)pseudo)[e];
}

// -------- basis precompute (CSR order): bas[e] = 12 f32 (9 basis, src bitcast in slot 9, pad)

__global__ void basis_kernel(const float2* __restrict__ ps_s, const int* __restrict__ src_s,
                             float4* __restrict__ bas, int E) {
  int e = blockIdx.x * blockDim.x + threadIdx.x;
  if (e >= E) return;
  float2 uv = ps_s[e];
  float u = uv.x, v = uv.y;
  float b0 = 0.5f * u * u - u + 0.5f, b1 = -u * u + u + 0.5f, b2 = 0.5f * u * u;
  float c0 = 0.5f * v * v - v + 0.5f, c1 = -v * v + v + 0.5f, c2 = 0.5f * v * v;
  size_t o = (size_t)e * 3;
  bas[o + 0] = make_float4(b0 * c0, b0 * c1, b0 * c2, b1 * c0);
  bas[o + 1] = make_float4(b1 * c1, b1 * c2, b2 * c0, b2 * c1);
  bas[o + 2] = make_float4(b2 * c2, __int_as_float(src_s[e]), 0.f, 0.f);
}

// -------- weight repack, TRANSPOSED: Wt[64 cols][640 k]; k 0..575 = W.flat, 576..639 = root

__global__ void wconv_kernel(const float* __restrict__ W, const float* __restrict__ root,
                             unsigned short* __restrict__ Wt) {
  int i = blockIdx.x * blockDim.x + threadIdx.x;
  if (i >= 640 * 64) return;
  int co = i / 640, r = i % 640;
  float v = (r < 576) ? W[r * 64 + co] : root[(r - 576) * 64 + co];
  Wt[i] = f2bf(v);
}

// -------- x -> bf16

__global__ void xconv_kernel(const float4* __restrict__ x4, ushort4* __restrict__ xh4, int n4) {
  int i = blockIdx.x * blockDim.x + threadIdx.x;
  if (i < n4) {
    float4 v = x4[i];
    ushort4 o;
    o.x = f2bf(v.x); o.y = f2bf(v.y); o.z = f2bf(v.z); o.w = f2bf(v.w);
    xh4[i] = o;
  }
}

// ---------------- per-node aggregation: one wave per node, lane = channel ----------------
// Inner loop: 3 wave-uniform basis loads + 1 gather + 9 FMAs per edge.

__global__ void agg_kernel(const int* __restrict__ offsets, const float4* __restrict__ bas,
                           const unsigned short* __restrict__ Xh,
                           unsigned short* __restrict__ A, int node0, int nodeEnd) {
  int wid = (blockIdx.x * blockDim.x + threadIdx.x) >> 6;
  int lane = threadIdx.x & 63;
  int n = node0 + wid;
  if (n >= nodeEnd) return;
  int beg = __builtin_amdgcn_readfirstlane(offsets[n]);
  int end = __builtin_amdgcn_readfirstlane(offsets[n + 1]);
  float a0 = 0.f, a1 = 0.f, a2 = 0.f, a3 = 0.f, a4 = 0.f,
        a5 = 0.f, a6 = 0.f, a7 = 0.f, a8 = 0.f;
  for (int j = beg; j < end; ++j) {
    float4 B0 = bas[(size_t)j * 3 + 0];
    float4 B1 = bas[(size_t)j * 3 + 1];
    float4 B2 = bas[(size_t)j * 3 + 2];
    int s = __builtin_amdgcn_readfirstlane(__float_as_int(B2.y));
    float xv = bf2f(Xh[(size_t)s * 64 + lane]);
    a0 += B0.x * xv; a1 += B0.y * xv; a2 += B0.z * xv; a3 += B0.w * xv;
    a4 += B1.x * xv; a5 += B1.y * xv; a6 += B1.z * xv; a7 += B1.w * xv;
    a8 += B2.x * xv;
  }
  float self = bf2f(Xh[(size_t)n * 64 + lane]);
  size_t row = (size_t)(n - node0) * 640;
  A[row + 0 * 64 + lane] = f2bf(a0);
  A[row + 1 * 64 + lane] = f2bf(a1);
  A[row + 2 * 64 + lane] = f2bf(a2);
  A[row + 3 * 64 + lane] = f2bf(a3);
  A[row + 4 * 64 + lane] = f2bf(a4);
  A[row + 5 * 64 + lane] = f2bf(a5);
  A[row + 6 * 64 + lane] = f2bf(a6);
  A[row + 7 * 64 + lane] = f2bf(a7);
  A[row + 8 * 64 + lane] = f2bf(a8);
  A[row + 576 + lane] = f2bf(self);
}

// ---------------- MFMA GEMM: [M,640](bf16) @ Wt^T + bias, relu ----------------

template <bool OUTBF16>
__global__ __launch_bounds__(256) void gemm_kernel(const unsigned short* __restrict__ A,
                                                   const unsigned short* __restrict__ Wt,
                                                   const float* __restrict__ bias,
                                                   void* __restrict__ outv, int M, int node0) {
  int tid = threadIdx.x;
  int w = tid >> 6, lane = tid & 63;
  int rowBase = blockIdx.x * 64 + w * 16;
  int rA = rowBase + (lane & 15);
  int kg = lane >> 4;
  const bool rowOK = rA < M;
  f32x4 acc[4] = {{0.f, 0.f, 0.f, 0.f}, {0.f, 0.f, 0.f, 0.f},
                  {0.f, 0.f, 0.f, 0.f}, {0.f, 0.f, 0.f, 0.f}};
#pragma unroll
  for (int kk = 0; kk < 20; ++kk) {
    int kbase = kk * 32 + kg * 8;
    bf16x8 af = {0, 0, 0, 0, 0, 0, 0, 0};
    if (rowOK) af = *(const bf16x8*)(A + (size_t)rA * 640 + kbase);
#pragma unroll
    for (int t = 0; t < 4; ++t) {
      bf16x8 bfr = *(const bf16x8*)(Wt + (size_t)(t * 16 + (lane & 15)) * 640 + kbase);
      acc[t] = __builtin_amdgcn_mfma_f32_16x16x32_bf16(af, bfr, acc[t], 0, 0, 0);
    }
  }
  int rowE0 = rowBase + (lane >> 4) * 4;  // C/D: col = lane&15, row = (lane>>4)*4 + reg
#pragma unroll
  for (int t = 0; t < 4; ++t) {
    int col = t * 16 + (lane & 15);
    float bv = bias[col];
#pragma unroll
    for (int r = 0; r < 4; ++r) {
      int row = rowE0 + r;
      if (row < M) {
        float val = fmaxf(acc[t][r] + bv, 0.f);
        size_t idx = (size_t)(node0 + row) * 64 + col;
        if (OUTBF16) ((unsigned short*)outv)[idx] = f2bf(val);
        else ((float*)outv)[idx] = val;
      }
    }
  }
}

// ---------------- host ----------------

extern "C" void kernel_launch(void* const* d_in, const int* in_sizes, int n_in,
                              void* d_out, int out_size, void* d_ws, size_t ws_size,
                              hipStream_t stream) {
  const float* x = (const float*)d_in[0];
  const int* ei = (const int*)d_in[1];
  const float* pseudo = (const float*)d_in[2];
  const float* W1 = (const float*)d_in[3];
  const float* root1 = (const float*)d_in[4];
  const float* b1 = (const float*)d_in[5];
  const float* W2 = (const float*)d_in[6];
  const float* root2 = (const float*)d_in[7];
  const float* b2 = (const float*)d_in[8];

  const int N = in_sizes[0] / 64;
  const int E = in_sizes[1] / 2;
  const int G = (N + 255) / 256;

  char* p = (char*)d_ws;
  auto carve = [&](size_t bytes) -> void* {
    void* r = (void*)p;
    p += (bytes + 255) & ~(size_t)255;
    return r;
  };
  int* counts = (int*)carve((size_t)N * 4);
  int* offsets = (int*)carve((size_t)(N + 1) * 4);
  int* cursor = (int*)carve((size_t)N * 4);
  int* bsum = (int*)carve((size_t)G * 4);
  int* src_s = (int*)carve((size_t)E * 4);
  float2* ps_s = (float2*)carve((size_t)E * 8);
  float4* bas = (float4*)carve((size_t)E * 48);
  unsigned short* Wt1 = (unsigned short*)carve(640 * 64 * 2);
  unsigned short* Wt2 = (unsigned short*)carve(640 * 64 * 2);
  unsigned short* h = (unsigned short*)carve((size_t)N * 64 * 2);
  unsigned short* xh = (unsigned short*)carve((size_t)N * 64 * 2);
  size_t used = (size_t)(p - (char*)d_ws);
  size_t avail = ws_size > used ? ws_size - used : 0;
  long long crMax = (long long)(avail / (640 * 2));
  int CR;
  if (crMax >= (long long)N) CR = N;
  else {
    CR = (int)crMax & ~63;
    if (CR < 64) CR = 64;
  }
  unsigned short* Agg = (unsigned short*)p;

  hipMemsetAsync(counts, 0, (size_t)N * 4, stream);
  count_kernel<<<(E + 255) / 256, 256, 0, stream>>>(ei, E, counts);
  scan1_kernel<<<G, 256, 0, stream>>>(counts, N, bsum);
  scan2_kernel<<<1, 512, 0, stream>>>(bsum, G);
  scan3_kernel<<<G, 256, 0, stream>>>(counts, N, bsum, offsets, cursor, E);
  fill_kernel<<<(E + 255) / 256, 256, 0, stream>>>(ei, pseudo, E, cursor, src_s, ps_s);
  basis_kernel<<<(E + 255) / 256, 256, 0, stream>>>(ps_s, src_s, bas, E);
  wconv_kernel<<<160, 256, 0, stream>>>(W1, root1, Wt1);
  wconv_kernel<<<160, 256, 0, stream>>>(W2, root2, Wt2);
  xconv_kernel<<<(N * 16 + 255) / 256, 256, 0, stream>>>((const float4*)x, (ushort4*)xh, N * 16);

  // layer 1: X = xh (bf16) -> h (bf16)
  for (int n0 = 0; n0 < N; n0 += CR) {
    int ncur = min(CR, N - n0);
    agg_kernel<<<(ncur + 3) / 4, 256, 0, stream>>>(offsets, bas, xh, Agg, n0, n0 + ncur);
    gemm_kernel<true><<<(ncur + 63) / 64, 256, 0, stream>>>(Agg, Wt1, b1, (void*)h, ncur, n0);
  }
  // layer 2: X = h (bf16) -> d_out (fp32)
  for (int n0 = 0; n0 < N; n0 += CR) {
    int ncur = min(CR, N - n0);
    agg_kernel<<<(ncur + 3) / 4, 256, 0, stream>>>(offsets, bas, h, Agg, n0, n0 + ncur);
    gemm_kernel<false><<<(ncur + 63) / 64, 256, 0, stream>>>(Agg, Wt2, b2, d_out, ncur, n0);
  }
}

// Round 5
// 428.638 us; speedup vs baseline: 1.5287x; 1.5287x over previous
//
#include <hip/hip_runtime.h>
#include <stdint.h>

typedef __attribute__((ext_vector_type(8))) short bf16x8;
typedef __attribute__((ext_vector_type(4))) float f32x4;

__device__ __forceinline__ float bf2f(unsigned short u) {
  union { unsigned int i; float f; } x; x.i = ((unsigned int)u) << 16; return x.f;
}
__device__ __forceinline__ unsigned short f2bf(float f) {
  union { float f; unsigned int i; } x; x.f = f;
  unsigned int i = x.i;
  return (unsigned short)((i + 0x7FFFu + ((i >> 16) & 1u)) >> 16);  // RNE
}

// ---------------- CSR build ----------------

__global__ void count_kernel(const int* __restrict__ ei, int E, int* __restrict__ counts) {
  int e = blockIdx.x * blockDim.x + threadIdx.x;
  if (e < E) atomicAdd(&counts[ei[E + e]], 1);
}

__global__ void scan1_kernel(const int* __restrict__ counts, int n, int* __restrict__ bsum) {
  int i = blockIdx.x * 256 + threadIdx.x;
  int v = (i < n) ? counts[i] : 0;
  int lane = threadIdx.x & 63, w = threadIdx.x >> 6;
  for (int d = 32; d > 0; d >>= 1) v += __shfl_down(v, d, 64);
  __shared__ int ws[4];
  if (lane == 0) ws[w] = v;
  __syncthreads();
  if (threadIdx.x == 0) bsum[blockIdx.x] = ws[0] + ws[1] + ws[2] + ws[3];
}

__global__ void scan2_kernel(int* __restrict__ bsum, int G) {
  int t = threadIdx.x;
  int c = (G + 511) >> 9;
  int lo = min(t * c, G), hi = min(lo + c, G);
  int s = 0;
  for (int i = lo; i < hi; ++i) s += bsum[i];
  int lane = t & 63, w = t >> 6;
  int incl = s;
  for (int d = 1; d < 64; d <<= 1) { int u = __shfl_up(incl, d, 64); if (lane >= d) incl += u; }
  __shared__ int wsum[8];
  if (lane == 63) wsum[w] = incl;
  __syncthreads();
  int wpre = 0;
  for (int i = 0; i < w; ++i) wpre += wsum[i];
  int excl = wpre + incl - s;
  for (int i = lo; i < hi; ++i) { int v = bsum[i]; bsum[i] = excl; excl += v; }
}

__global__ void scan3_kernel(const int* __restrict__ counts, int n, const int* __restrict__ bsum,
                             int* __restrict__ offsets, int* __restrict__ cursor, int total) {
  int i = blockIdx.x * 256 + threadIdx.x;
  int v = (i < n) ? counts[i] : 0;
  int lane = threadIdx.x & 63, w = threadIdx.x >> 6;
  int incl = v;
  for (int d = 1; d < 64; d <<= 1) { int u = __shfl_up(incl, d, 64); if (lane >= d) incl += u; }
  __shared__ int wsum[4];
  if (lane == 63) wsum[w] = incl;
  __syncthreads();
  int pre = bsum[blockIdx.x];
  for (int j = 0; j < w; ++j) pre += wsum[j];
  if (i < n) {
    int excl = pre + incl - v;
    offsets[i] = excl;
    cursor[i] = excl;
  }
  if (i == 0) offsets[n] = total;
}

// fill: CSR scatter + rank-1 basis factors (b0,b1,b2,c0,c1,c2) folded in.
// src kept in a SEPARATE array so the x-gather address never depends on the basis load.

__global__ void fill_kernel(const int* __restrict__ ei, const float* __restrict__ pseudo,
                            int E, int* __restrict__ cursor, int* __restrict__ src_s,
                            float2* __restrict__ bas) {
  int e = blockIdx.x * blockDim.x + threadIdx.x;
  if (e >= E) return;
  int d = ei[E + e];
  int s = ei[e];
  float2 uv = ((const float2*)pseudo)[e];
  float u = uv.x, v = uv.y;
  float b0 = 0.5f * u * u - u + 0.5f, b1 = -u * u + u + 0.5f, b2 = 0.5f * u * u;
  float c0 = 0.5f * v * v - v + 0.5f, c1 = -v * v + v + 0.5f, c2 = 0.5f * v * v;
  int p = atomicAdd(&cursor[d], 1);
  src_s[p] = s;
  size_t o = (size_t)p * 3;
  bas[o + 0] = make_float2(b0, b1);
  bas[o + 1] = make_float2(b2, c0);
  bas[o + 2] = make_float2(c1, c2);
}

// -------- weight repack, TRANSPOSED: Wt[64 cols][640 k]; k 0..575 = W.flat, 576..639 = root

__global__ void wconv_kernel(const float* __restrict__ W, const float* __restrict__ root,
                             unsigned short* __restrict__ Wt) {
  int i = blockIdx.x * blockDim.x + threadIdx.x;
  if (i >= 640 * 64) return;
  int co = i / 640, r = i % 640;
  float v = (r < 576) ? W[r * 64 + co] : root[(r - 576) * 64 + co];
  Wt[i] = f2bf(v);
}

// -------- x -> bf16

__global__ void xconv_kernel(const float4* __restrict__ x4, ushort4* __restrict__ xh4, int n4) {
  int i = blockIdx.x * blockDim.x + threadIdx.x;
  if (i < n4) {
    float4 v = x4[i];
    ushort4 o;
    o.x = f2bf(v.x); o.y = f2bf(v.y); o.z = f2bf(v.z); o.w = f2bf(v.w);
    xh4[i] = o;
  }
}

// ---------------- fused agg + GEMM ----------------
// Block 256 = 4 waves, 16 nodes/block. Wave w aggregates nodes w*4..w*4+3 (lane = channel,
// ×4-batched edge loop for MLP) into LDS tile sA[16][648] (pad -> 16B-aligned rows).
// After one barrier, wave w computes the 16x16 output tile for cols w*16..w*16+15 via MFMA.

#define SROW 648

#define EDGE_FMA(Q0, Q1, Q2, XV)                                   \
  {                                                                \
    float t0 = Q0.x * XV, t1 = Q0.y * XV, t2 = Q1.x * XV;          \
    a0 += t0 * Q1.y; a1 += t0 * Q2.x; a2 += t0 * Q2.y;             \
    a3 += t1 * Q1.y; a4 += t1 * Q2.x; a5 += t1 * Q2.y;             \
    a6 += t2 * Q1.y; a7 += t2 * Q2.x; a8 += t2 * Q2.y;             \
  }

template <bool OUTBF16>
__global__ __launch_bounds__(256) void fused_kernel(const int* __restrict__ offsets,
                                                    const int* __restrict__ src_s,
                                                    const float2* __restrict__ bas,
                                                    const unsigned short* __restrict__ Xh,
                                                    const unsigned short* __restrict__ Wt,
                                                    const float* __restrict__ bias,
                                                    void* __restrict__ outv, int N) {
  __shared__ short sA[16 * SROW];
  int tid = threadIdx.x, w = tid >> 6, lane = tid & 63;
  int nodeBase = blockIdx.x * 16;

  for (int t = 0; t < 4; ++t) {
    int row = w * 4 + t;
    int n = nodeBase + row;
    if (n >= N) continue;
    int beg = __builtin_amdgcn_readfirstlane(offsets[n]);
    int end = __builtin_amdgcn_readfirstlane(offsets[n + 1]);
    float a0 = 0.f, a1 = 0.f, a2 = 0.f, a3 = 0.f, a4 = 0.f,
          a5 = 0.f, a6 = 0.f, a7 = 0.f, a8 = 0.f;
    int j = beg;
    for (; j + 4 <= end; j += 4) {
      int s0 = src_s[j], s1 = src_s[j + 1], s2 = src_s[j + 2], s3 = src_s[j + 3];
      size_t o = (size_t)j * 3;
      float2 q00 = bas[o + 0], q01 = bas[o + 1], q02 = bas[o + 2];
      float2 q10 = bas[o + 3], q11 = bas[o + 4], q12 = bas[o + 5];
      float2 q20 = bas[o + 6], q21 = bas[o + 7], q22 = bas[o + 8];
      float2 q30 = bas[o + 9], q31 = bas[o + 10], q32 = bas[o + 11];
      float xv0 = bf2f(Xh[(size_t)s0 * 64 + lane]);
      float xv1 = bf2f(Xh[(size_t)s1 * 64 + lane]);
      float xv2 = bf2f(Xh[(size_t)s2 * 64 + lane]);
      float xv3 = bf2f(Xh[(size_t)s3 * 64 + lane]);
      EDGE_FMA(q00, q01, q02, xv0);
      EDGE_FMA(q10, q11, q12, xv1);
      EDGE_FMA(q20, q21, q22, xv2);
      EDGE_FMA(q30, q31, q32, xv3);
    }
    for (; j < end; ++j) {
      int s0 = src_s[j];
      size_t o = (size_t)j * 3;
      float2 q00 = bas[o + 0], q01 = bas[o + 1], q02 = bas[o + 2];
      float xv0 = bf2f(Xh[(size_t)s0 * 64 + lane]);
      EDGE_FMA(q00, q01, q02, xv0);
    }
    float self = bf2f(Xh[(size_t)n * 64 + lane]);
    int rb = row * SROW;
    sA[rb + 0 * 64 + lane] = (short)f2bf(a0);
    sA[rb + 1 * 64 + lane] = (short)f2bf(a1);
    sA[rb + 2 * 64 + lane] = (short)f2bf(a2);
    sA[rb + 3 * 64 + lane] = (short)f2bf(a3);
    sA[rb + 4 * 64 + lane] = (short)f2bf(a4);
    sA[rb + 5 * 64 + lane] = (short)f2bf(a5);
    sA[rb + 6 * 64 + lane] = (short)f2bf(a6);
    sA[rb + 7 * 64 + lane] = (short)f2bf(a7);
    sA[rb + 8 * 64 + lane] = (short)f2bf(a8);
    sA[rb + 576 + lane] = (short)f2bf(self);
  }
  __syncthreads();

  // ---- GEMM phase: 16 rows (block nodes) x 16 cols (w*16..), K=640
  int r15 = lane & 15, kg = lane >> 4;
  f32x4 acc = {0.f, 0.f, 0.f, 0.f};
#pragma unroll
  for (int kk = 0; kk < 20; ++kk) {
    int kbase = kk * 32 + kg * 8;
    bf16x8 af = *(const bf16x8*)(&sA[r15 * SROW + kbase]);
    bf16x8 bfr = *(const bf16x8*)(Wt + (size_t)(w * 16 + r15) * 640 + kbase);
    acc = __builtin_amdgcn_mfma_f32_16x16x32_bf16(af, bfr, acc, 0, 0, 0);
  }
  // C/D: col = lane&15, row = (lane>>4)*4 + reg
  int col = w * 16 + r15;
  float bv = bias[col];
  int row0 = kg * 4;
#pragma unroll
  for (int r = 0; r < 4; ++r) {
    int node = nodeBase + row0 + r;
    if (node < N) {
      float val = fmaxf(acc[r] + bv, 0.f);
      size_t idx = (size_t)node * 64 + col;
      if (OUTBF16) ((unsigned short*)outv)[idx] = f2bf(val);
      else ((float*)outv)[idx] = val;
    }
  }
}

// ---------------- host ----------------

extern "C" void kernel_launch(void* const* d_in, const int* in_sizes, int n_in,
                              void* d_out, int out_size, void* d_ws, size_t ws_size,
                              hipStream_t stream) {
  const float* x = (const float*)d_in[0];
  const int* ei = (const int*)d_in[1];
  const float* pseudo = (const float*)d_in[2];
  const float* W1 = (const float*)d_in[3];
  const float* root1 = (const float*)d_in[4];
  const float* b1 = (const float*)d_in[5];
  const float* W2 = (const float*)d_in[6];
  const float* root2 = (const float*)d_in[7];
  const float* b2 = (const float*)d_in[8];

  const int N = in_sizes[0] / 64;
  const int E = in_sizes[1] / 2;
  const int G = (N + 255) / 256;

  char* p = (char*)d_ws;
  auto carve = [&](size_t bytes) -> void* {
    void* r = (void*)p;
    p += (bytes + 255) & ~(size_t)255;
    return r;
  };
  int* counts = (int*)carve((size_t)N * 4);
  int* offsets = (int*)carve((size_t)(N + 1) * 4);
  int* cursor = (int*)carve((size_t)N * 4);
  int* bsum = (int*)carve((size_t)G * 4);
  int* src_s = (int*)carve((size_t)E * 4);
  float2* bas = (float2*)carve((size_t)E * 24);
  unsigned short* Wt1 = (unsigned short*)carve(640 * 64 * 2);
  unsigned short* Wt2 = (unsigned short*)carve(640 * 64 * 2);
  unsigned short* h = (unsigned short*)carve((size_t)N * 64 * 2);
  unsigned short* xh = (unsigned short*)carve((size_t)N * 64 * 2);
  (void)ws_size;

  hipMemsetAsync(counts, 0, (size_t)N * 4, stream);
  count_kernel<<<(E + 255) / 256, 256, 0, stream>>>(ei, E, counts);
  scan1_kernel<<<G, 256, 0, stream>>>(counts, N, bsum);
  scan2_kernel<<<1, 512, 0, stream>>>(bsum, G);
  scan3_kernel<<<G, 256, 0, stream>>>(counts, N, bsum, offsets, cursor, E);
  fill_kernel<<<(E + 255) / 256, 256, 0, stream>>>(ei, pseudo, E, cursor, src_s, bas);
  wconv_kernel<<<160, 256, 0, stream>>>(W1, root1, Wt1);
  wconv_kernel<<<160, 256, 0, stream>>>(W2, root2, Wt2);
  xconv_kernel<<<(N * 16 + 255) / 256, 256, 0, stream>>>((const float4*)x, (ushort4*)xh, N * 16);

  int FB = (N + 15) / 16;
  // layer 1: xh (bf16) -> h (bf16)
  fused_kernel<true><<<FB, 256, 0, stream>>>(offsets, src_s, bas, xh, Wt1, b1, (void*)h, N);
  // layer 2: h (bf16) -> d_out (fp32)
  fused_kernel<false><<<FB, 256, 0, stream>>>(offsets, src_s, bas, h, Wt2, b2, d_out, N);
}